// Round 5
// baseline (1093.046 us; speedup 1.0000x reference)
//
#include <hip/hip_runtime.h>
#include <hip/hip_bf16.h>

typedef unsigned long long u64;

static constexpr int NF = 27552;              // 2*13776 faces
static constexpr int IMGOFF = 3 * 256 * 256;  // image elements before textures
static constexpr int NSLICE = 16;             // list-slices per tile
static constexpr int CAPMAX = 6144;           // per-tile list capacity (max)

#define EYEZ 2.7320508075688772f   // -(EYE.z) = 1/tan(30deg)+1, fp64->fp32

// ws layout (bytes):
static constexpr size_t OFF_KEYS = 0;         // 65536 u64
static constexpr size_t OFF_FCNT = 524288;    // int
static constexpr size_t OFF_CNT  = 524352;    // 1024 int per-tile counts
static constexpr size_t OFF_FDAT = 528448;    // NF*16 f32 (orig-indexed)
static constexpr size_t OFF_CF   = 2291776;   // NF*16 f32 (front-compacted)
static constexpr size_t OFF_CBB  = 4055104;   // NF float4 bboxes (compacted)
static constexpr size_t OFF_LIST = 4495936;   // 1024*cap int

static constexpr u64 FARKEY = ((u64)0x42C80000u << 32);  // depth=100.0f, id 0

// ---------------------------------------------------------------------------
// Kernel 0: init keys to FAR, zero per-tile counts and compaction counter.
// ---------------------------------------------------------------------------
__global__ __launch_bounds__(256) void init_ws(u64* __restrict__ keys,
                                               int* __restrict__ fcnt,
                                               int* __restrict__ cnt)
{
    int i = blockIdx.x * 256 + threadIdx.x;
    keys[i] = FARKEY;
    if (i < 1024) cnt[i] = 0;
    if (i == 0) *fcnt = 0;
}

// ---------------------------------------------------------------------------
// Kernel 1: per-face rasterization constants (orig-indexed, for epilogue)
// + compacted front-face list {a,b,c,ds,iz,id} + bbox.  All fp ops replicate
// numpy's op order exactly (no FMA contraction) so the per-pixel depth
// argmin is bit-identical to the fp32 reference.
// fdat/cf[f*16]: a0,a1,a2,b0,b1,b2,c0,c1,c2,det_safe,iz0,iz1,iz2,(z0|id),z1,z2
// ---------------------------------------------------------------------------
__global__ __launch_bounds__(256) void face_prep(
    const float* __restrict__ cam,
    const float* __restrict__ verts,
    const int* __restrict__ faces,
    float* __restrict__ fdat,
    float* __restrict__ cf,
    float4* __restrict__ cbb,
    int* __restrict__ fcnt)
{
    int f = blockIdx.x * 256 + threadIdx.x;
    if (f >= NF) return;
    float c0 = cam[0], c1 = cam[1], c2 = cam[2];
    // replicate np look_at rounding exactly (these are 1.0 in binary FP, free)
    float z3 = __fdiv_rn(EYEZ, __fsqrt_rn(__fmul_rn(EYEZ, EYEZ)));
    float x0r = __fdiv_rn(z3, __fsqrt_rn(__fmul_rn(z3, z3)));
    float wyy = __fmul_rn(z3, x0r);
    float y1r = __fdiv_rn(wyy, __fsqrt_rn(__fmul_rn(wyy, wyy)));

    float xs[3], ys[3], zs[3];
#pragma unroll
    for (int i = 0; i < 3; i++) {
        int vi = faces[f * 3 + i];
        float vx = verts[vi * 3 + 0];
        float vy = verts[vi * 3 + 1];
        float vz = verts[vi * 3 + 2];
        float px = __fmul_rn(c0, __fadd_rn(vx, c1));
        float py = __fmul_rn(c0, __fadd_rn(vy, c2));
        xs[i] = __fmul_rn(px, x0r);
        ys[i] = __fmul_rn(-py, y1r);
        zs[i] = __fmul_rn(__fadd_rn(vz, EYEZ), z3);
    }
    float a0 = __fsub_rn(ys[1], ys[2]);
    float a1 = __fsub_rn(ys[2], ys[0]);
    float a2 = __fsub_rn(ys[0], ys[1]);
    float b0 = __fsub_rn(xs[2], xs[1]);
    float b1 = __fsub_rn(xs[0], xs[2]);
    float b2 = __fsub_rn(xs[1], xs[0]);
    float cc0 = __fsub_rn(__fmul_rn(xs[1], ys[2]), __fmul_rn(xs[2], ys[1]));
    float cc1 = __fsub_rn(__fmul_rn(xs[2], ys[0]), __fmul_rn(xs[0], ys[2]));
    float cc2 = __fsub_rn(__fmul_rn(xs[0], ys[1]), __fmul_rn(xs[1], ys[0]));
    float det = __fadd_rn(__fadd_rn(cc0, cc1), cc2);
    float ds  = (fabsf(det) > 1e-10f) ? det : 1e-10f;
    float z0 = (fabsf(zs[0]) > 1e-6f) ? zs[0] : 1e-6f;
    float z1 = (fabsf(zs[1]) > 1e-6f) ? zs[1] : 1e-6f;
    float z2 = (fabsf(zs[2]) > 1e-6f) ? zs[2] : 1e-6f;
    float iz0 = __fdiv_rn(1.0f, z0);
    float iz1 = __fdiv_rn(1.0f, z1);
    float iz2 = __fdiv_rn(1.0f, z2);

    float* o = fdat + (size_t)f * 16;
    o[0] = a0; o[1] = a1; o[2] = a2;
    o[3] = b0; o[4] = b1; o[5] = b2;
    o[6] = cc0; o[7] = cc1; o[8] = cc2;
    o[9] = ds;
    o[10] = iz0; o[11] = iz1; o[12] = iz2;
    o[13] = z0; o[14] = z1; o[15] = z2;

    if (det > 0.0f) {   // back faces can never be `valid` -> exact cull
        int pos = atomicAdd(fcnt, 1);
        float* q = cf + (size_t)pos * 16;
        q[0] = a0; q[1] = a1; q[2] = a2;
        q[3] = b0; q[4] = b1; q[5] = b2;
        q[6] = cc0; q[7] = cc1; q[8] = cc2;
        q[9] = ds;
        q[10] = iz0; q[11] = iz1; q[12] = iz2;
        q[13] = __int_as_float(f);
        q[14] = 0.0f; q[15] = 0.0f;
        float4 bb;
        bb.x = fminf(fminf(xs[0], xs[1]), xs[2]) - 1e-4f;
        bb.y = fmaxf(fmaxf(xs[0], xs[1]), xs[2]) + 1e-4f;
        bb.z = fminf(fminf(ys[0], ys[1]), ys[2]) - 1e-4f;
        bb.w = fmaxf(fmaxf(ys[0], ys[1]), ys[2]) + 1e-4f;
        cbb[pos] = bb;
    }
}

// ---------------------------------------------------------------------------
// Kernel 2: 9 bilinear texture samples per face -> textures output (fp32).
// lighting() is the identity (DIR_INT=0, AMB=1).  3rd TS dim is broadcast.
// ---------------------------------------------------------------------------
__global__ __launch_bounds__(256) void tex_sample(
    const float* __restrict__ cam,
    const float* __restrict__ verts,
    const int* __restrict__ faces,
    const float* __restrict__ uv,
    float* __restrict__ out_tex)
{
    int id = blockIdx.x * 256 + threadIdx.x;
    if (id >= NF * 9) return;
    int f = id / 9, t = id - f * 9;
    float c0 = cam[0], c1 = cam[1], c2 = cam[2];
    float px[3], py[3];
#pragma unroll
    for (int i = 0; i < 3; i++) {
        int vi = faces[f * 3 + i];
        px[i] = __fmul_rn(c0, __fadd_rn(verts[vi * 3 + 0], c1));
        py[i] = __fmul_rn(c0, __fadd_rn(verts[vi * 3 + 1], c2));
    }
    const float abv[3] = {0.0f, 0.5f, 1.0f};
    int t1 = t / 3, t2 = t - t1 * 3;
    float uu = abv[t1], vv = abv[t2];
    float sx = __fadd_rn(__fadd_rn(__fmul_rn(__fsub_rn(px[0], px[2]), uu),
                                   __fmul_rn(__fsub_rn(px[1], px[2]), vv)), px[2]);
    float sy = __fadd_rn(__fadd_rn(__fmul_rn(__fsub_rn(py[0], py[2]), uu),
                                   __fmul_rn(__fsub_rn(py[1], py[2]), vv)), py[2]);
    sx = fminf(fmaxf(sx, -1.0f), 1.0f);
    sy = fminf(fmaxf(sy, -1.0f), 1.0f);
    float xg = __fmul_rn(__fmul_rn(__fadd_rn(sx, 1.0f), 0.5f), 255.0f);
    float yg = __fmul_rn(__fmul_rn(__fadd_rn(sy, 1.0f), 0.5f), 255.0f);
    float x0f = floorf(xg), y0f = floorf(yg);
    float wx = __fsub_rn(xg, x0f), wy = __fsub_rn(yg, y0f);
    int x0 = (int)x0f; x0 = x0 < 0 ? 0 : (x0 > 255 ? 255 : x0);
    int y0 = (int)y0f; y0 = y0 < 0 ? 0 : (y0 > 255 ? 255 : y0);
    int x1 = x0 + 1 > 255 ? 255 : x0 + 1;
    int y1 = y0 + 1 > 255 ? 255 : y0 + 1;
    float omwx = __fsub_rn(1.0f, wx), omwy = __fsub_rn(1.0f, wy);
    float w00 = __fmul_rn(omwx, omwy);
    float w10 = __fmul_rn(wx, omwy);
    float w01 = __fmul_rn(omwx, wy);
    float w11 = __fmul_rn(wx, wy);
    size_t tb = (size_t)f * 81 + (size_t)t1 * 27 + (size_t)t2 * 9;
#pragma unroll
    for (int c = 0; c < 3; c++) {
        const float* img = uv + c * 65536;
        float g00 = img[y0 * 256 + x0];
        float g10 = img[y0 * 256 + x1];
        float g01 = img[y1 * 256 + x0];
        float g11 = img[y1 * 256 + x1];
        float val = __fmul_rn(g00, w00);
        val = __fadd_rn(val, __fmul_rn(g10, w10));
        val = __fadd_rn(val, __fmul_rn(g01, w01));
        val = __fadd_rn(val, __fmul_rn(g11, w11));
        out_tex[tb + 0 + c] = val;   // k = 0,1,2 broadcast
        out_tex[tb + 3 + c] = val;
        out_tex[tb + 6 + c] = val;
    }
}

// ---------------------------------------------------------------------------
// Kernel 3: binning. Thread = (compacted face p, tile-row jy). Tests the
// 3-edge SAT upper bound per tile column (linearized: 3 FMA + 3 cmp) within
// the face's bbox column range, appends p to the tile's list. Conservative
// margin 1e-3 >> fp error (~1e-5): the list is a SUPERSET of every
// (face,tile) numpy accepts; extra entries are scored by the identical
// formula, so they can never diverge from the reference.
// ---------------------------------------------------------------------------
__global__ __launch_bounds__(256) void bin_faces(
    const float* __restrict__ cf,
    const float4* __restrict__ cbb,
    const int* __restrict__ fcnt,
    int* __restrict__ cnt,
    int* __restrict__ list,
    int cap)
{
    int gid = blockIdx.x * 256 + threadIdx.x;
    int p = gid >> 5, jy = gid & 31;
    if (p >= *fcnt) return;
    float4 bb = cbb[p];
    float ylo = (float)(16 * jy + 1 - 256) * (1.0f / 256.0f);
    float yhi = (float)(16 * jy + 15 - 256) * (1.0f / 256.0f);
    if (yhi < bb.z || ylo > bb.w) return;

    const float4* q = (const float4*)(cf + (size_t)p * 16);
    float4 q0 = q[0], q1 = q[1], q2 = q[2];
    float a0 = q0.x, a1 = q0.y, a2 = q0.z;
    float b0 = q0.w, b1 = q1.x, b2 = q1.y;
    float c0 = q1.z, c1 = q1.w, c2 = q2.x;

    // per-edge: max over tile rect of (a*x + b*y + c) = A*jx + B
    float K0 = fmaxf(b0 * ylo, b0 * yhi) + c0;
    float K1 = fmaxf(b1 * ylo, b1 * yhi) + c1;
    float K2 = fmaxf(b2 * ylo, b2 * yhi) + c2;
    float A0 = a0 * (1.0f / 16.0f);
    float A1 = a1 * (1.0f / 16.0f);
    float A2 = a2 * (1.0f / 16.0f);
    float B0 = a0 * (((a0 > 0.f ? 15.f : 1.f) - 256.f) * (1.0f / 256.0f)) + K0;
    float B1 = a1 * (((a1 > 0.f ? 15.f : 1.f) - 256.f) * (1.0f / 256.0f)) + K1;
    float B2 = a2 * (((a2 > 0.f ? 15.f : 1.f) - 256.f) * (1.0f / 256.0f)) + K2;

    int jx0 = (int)floorf(16.0f * bb.x + 15.0625f);
    int jx1 = (int)floorf(16.0f * bb.y + 15.9375f) + 1;
    jx0 = jx0 < 0 ? 0 : jx0;
    jx1 = jx1 > 31 ? 31 : jx1;
    int rowbase = jy * 32;
    for (int jx = jx0; jx <= jx1; jx++) {
        float jf = (float)jx;
        bool pass = (fmaf(jf, A0, B0) >= -1e-3f) &&
                    (fmaf(jf, A1, B1) >= -1e-3f) &&
                    (fmaf(jf, A2, B2) >= -1e-3f);
        if (pass) {
            int pos = atomicAdd(&cnt[rowbase + jx], 1);
            if (pos < cap) list[(size_t)(rowbase + jx) * cap + pos] = p;
        }
    }
}

// ---------------------------------------------------------------------------
// Kernel 4: depth argmin over pre-binned lists. Wave = (8x8 tile, slice).
// Per 64-entry chunk: coalesced id load + 64B/lane face gather -> LDS
// (transposed float4-column layout: writes 8-way max, uniform reads
// broadcast-free), then score all 64 with the bit-exact numpy path.
// No culling, no barriers. Winner via global u64 atomicMin.
// ---------------------------------------------------------------------------
__global__ __launch_bounds__(256, 8) void raster_score(
    const float* __restrict__ cf,
    const int* __restrict__ cnt,
    const int* __restrict__ list,
    int cap,
    u64* __restrict__ keys)
{
    __shared__ __align__(16) float sface[4][1024];   // [wave][q*256 + s*4]
    const int lane = threadIdx.x & 63;
    const int wid  = threadIdx.x >> 6;
    const int gw = blockIdx.x * 4 + wid;             // 0..16383
    const int tile = gw & 1023;
    const int slice = gw >> 10;                      // 16 slices
    const int tx = tile & 31, ty = tile >> 5;
    const int pxi = tx * 8 + (lane & 7), pyi = ty * 8 + (lane >> 3);
    const float xp = (float)(2 * pxi + 1 - 256) * (1.0f / 256.0f);  // exact
    const float yp = (float)(2 * pyi + 1 - 256) * (1.0f / 256.0f);
    float* sf = sface[wid];

    int len = cnt[tile];
    if (len > cap) len = cap;
    const int per = (len + NSLICE - 1) / NSLICE;
    const int s0 = slice * per;
    const int s1 = (s0 + per < len) ? s0 + per : len;
    if (s0 >= s1) return;
    const int* tl = list + (size_t)tile * cap;

    u64 best = FARKEY;

    // preload chunk 0
    bool cv = (s0 + lane) < s1;
    float4 r0, r1, r2, r3;
    if (cv) {
        int cid = tl[s0 + lane];
        const float4* fp4 = (const float4*)(cf + (size_t)cid * 16);
        r0 = fp4[0]; r1 = fp4[1]; r2 = fp4[2]; r3 = fp4[3];
    }

    for (int cb = s0; cb < s1; cb += 64) {
        int m = s1 - cb; if (m > 64) m = 64;
        // stage current chunk (transposed)
        if (cv) {
            *(float4*)(sf +   0 + lane * 4) = r0;
            *(float4*)(sf + 256 + lane * 4) = r1;
            *(float4*)(sf + 512 + lane * 4) = r2;
            *(float4*)(sf + 768 + lane * 4) = r3;
        }
        // prefetch next chunk (id load + gather; hidden under inner loop of
        // this chunk on other waves / next iteration's waitcnt)
        int nb = cb + 64;
        cv = false;
        if (nb < s1) {
            cv = (nb + lane) < s1;
            if (cv) {
                int nid = tl[nb + lane];
                const float4* fp4 = (const float4*)(cf + (size_t)nid * 16);
                r0 = fp4[0]; r1 = fp4[1]; r2 = fp4[2]; r3 = fp4[3];
            }
        }
        asm volatile("s_waitcnt lgkmcnt(0)" ::: "memory");  // ds_writes done
        // score every entry: bit-exact numpy path
        for (int j = 0; j < m; j++) {
            const float* fb = sf + 4 * j;
            float4 q0 = *(const float4*)(fb + 0);
            float4 q1 = *(const float4*)(fb + 256);
            float4 q2 = *(const float4*)(fb + 512);
            float2 q3 = *(const float2*)(fb + 768);
            float t0 = __fadd_rn(__fadd_rn(__fmul_rn(xp, q0.x), __fmul_rn(yp, q0.w)), q1.z);
            float t1 = __fadd_rn(__fadd_rn(__fmul_rn(xp, q0.y), __fmul_rn(yp, q1.x)), q1.w);
            float t2 = __fadd_rn(__fadd_rn(__fmul_rn(xp, q0.z), __fmul_rn(yp, q1.y)), q2.x);
            // ds>0 for all staged faces => sign(w)==sign(t): exact w>=0 test
            bool in = !(t0 < 0.0f) && !(t1 < 0.0f) && !(t2 < 0.0f);
            if (!__any(in)) continue;
            float dsf = q2.y;
            float w0 = __fdiv_rn(t0, dsf);
            float w1 = __fdiv_rn(t1, dsf);
            float w2 = __fdiv_rn(t2, dsf);
            in = in && !(w0 > 1.0f) && !(w1 > 1.0f) && !(w2 > 1.0f);
            float den = __fmul_rn(w0, q2.z);
            den = __fadd_rn(den, __fmul_rn(w1, q2.w));
            den = __fadd_rn(den, __fmul_rn(w2, q3.x));
            if (in && den > 1e-8f) {
                float zp = __fdiv_rn(1.0f, den);
                if (zp > 0.1f && zp < 100.0f) {
                    u64 key = ((u64)__float_as_uint(zp) << 32)
                            | (u64)(unsigned)__float_as_int(q3.y);
                    if (key < best) best = key;
                }
            }
        }
    }
    if (best != FARKEY)
        atomicMin(&keys[(size_t)pyi * 256 + pxi], best);
}

// ---------------------------------------------------------------------------
// Kernel 5: per-pixel epilogue — recompute exact barycentrics for the winner
// and trilinear-sample the face texture (numpy op order, bit-exact path).
// ---------------------------------------------------------------------------
__global__ __launch_bounds__(256) void epilogue(
    const u64* __restrict__ keys,
    const float* __restrict__ fdat,
    const float* __restrict__ tex,   // d_out + IMGOFF, from tex_sample
    float* __restrict__ out_img)
{
    int pix = blockIdx.x * 256 + threadIdx.x;   // 65536
    int xo = pix & 255, yo = pix >> 8;
    const float xp = (float)(2 * xo + 1 - 256) * (1.0f / 256.0f);
    const float yp = (float)(2 * yo + 1 - 256) * (1.0f / 256.0f);
    u64 m = keys[pix];
    float depth = __uint_as_float((unsigned)(m >> 32));
    float col0 = 0.f, col1 = 0.f, col2 = 0.f;
    if (depth < 100.0f) {
        int fidx = (int)(unsigned)(m & 0xFFFFFFFFu);
        const float* fd = fdat + (size_t)fidx * 16;
        float t0 = __fadd_rn(__fadd_rn(__fmul_rn(xp, fd[0]), __fmul_rn(yp, fd[3])), fd[6]);
        float t1 = __fadd_rn(__fadd_rn(__fmul_rn(xp, fd[1]), __fmul_rn(yp, fd[4])), fd[7]);
        float t2 = __fadd_rn(__fadd_rn(__fmul_rn(xp, fd[2]), __fmul_rn(yp, fd[5])), fd[8]);
        float dsf = fd[9];
        float w0 = __fdiv_rn(t0, dsf), w1 = __fdiv_rn(t1, dsf), w2 = __fdiv_rn(t2, dsf);
        float wc0 = __fdiv_rn(w0, fd[13]);
        float wc1 = __fdiv_rn(w1, fd[14]);
        float wc2 = __fdiv_rn(w2, fd[15]);
        float ssum = __fadd_rn(__fadd_rn(wc0, wc1), wc2);
        float dnm = fmaxf(ssum, 1e-8f);
        wc0 = __fdiv_rn(wc0, dnm); wc1 = __fdiv_rn(wc1, dnm); wc2 = __fdiv_rn(wc2, dnm);
        float pos0 = __fmul_rn(fminf(fmaxf(wc0, 0.f), 1.f), 2.0f);
        float pos1 = __fmul_rn(fminf(fmaxf(wc1, 0.f), 1.f), 2.0f);
        float pos2 = __fmul_rn(fminf(fmaxf(wc2, 0.f), 1.f), 2.0f);
        float lf0 = fminf(fmaxf(floorf(pos0), 0.f), 2.f);
        float lf1 = fminf(fmaxf(floorf(pos1), 0.f), 2.f);
        float lf2 = fminf(fmaxf(floorf(pos2), 0.f), 2.f);
        float fr0 = __fsub_rn(pos0, lf0), fr1 = __fsub_rn(pos1, lf1), fr2 = __fsub_rn(pos2, lf2);
        int lo0 = (int)lf0, lo1 = (int)lf1;
        int hi0 = lo0 + 1 > 2 ? 2 : lo0 + 1;
        int hi1 = lo1 + 1 > 2 ? 2 : lo1 + 1;
        const float* tbase = tex + (size_t)fidx * 81;
#pragma unroll
        for (int bits = 0; bits < 8; bits++) {
            int u0 = bits & 1, u1 = (bits >> 1) & 1, u2 = (bits >> 2) & 1;
            int i0 = u0 ? hi0 : lo0;
            int i1 = u1 ? hi1 : lo1;
            float e0 = u0 ? fr0 : __fsub_rn(1.0f, fr0);
            float e1 = u1 ? fr1 : __fsub_rn(1.0f, fr1);
            float e2 = u2 ? fr2 : __fsub_rn(1.0f, fr2);
            float wgt = __fmul_rn(__fmul_rn(e0, e1), e2);
            const float* tp = tbase + (size_t)i0 * 27 + (size_t)i1 * 9;  // k broadcast
            col0 = __fadd_rn(col0, __fmul_rn(wgt, tp[0]));
            col1 = __fadd_rn(col1, __fmul_rn(wgt, tp[1]));
            col2 = __fadd_rn(col2, __fmul_rn(wgt, tp[2]));
        }
    }
    out_img[pix]          = col0;
    out_img[65536 + pix]  = col1;
    out_img[131072 + pix] = col2;
}

extern "C" void kernel_launch(void* const* d_in, const int* in_sizes, int n_in,
                              void* d_out, int out_size, void* d_ws, size_t ws_size,
                              hipStream_t stream) {
    const float* cam   = (const float*)d_in[0];
    const float* verts = (const float*)d_in[1];
    const float* uv    = (const float*)d_in[2];
    const int*   faces = (const int*)d_in[3];
    float* out = (float*)d_out;

    char* ws = (char*)d_ws;
    u64*    keys = (u64*)(ws + OFF_KEYS);
    int*    fcnt = (int*)(ws + OFF_FCNT);
    int*    cnt  = (int*)(ws + OFF_CNT);
    float*  fdat = (float*)(ws + OFF_FDAT);
    float*  cf   = (float*)(ws + OFF_CF);
    float4* cbb  = (float4*)(ws + OFF_CBB);
    int*    list = (int*)(ws + OFF_LIST);

    int cap = CAPMAX;
    if (ws_size > OFF_LIST) {
        size_t avail = (ws_size - OFF_LIST) / (1024 * sizeof(int));
        if ((size_t)cap > avail) cap = (int)avail;
    } else {
        cap = 0;
    }

    float* out_img = out;            // 3*256*256
    float* out_tex = out + IMGOFF;   // NF*81

    hipLaunchKernelGGL(init_ws, dim3(256), dim3(256), 0, stream, keys, fcnt, cnt);
    hipLaunchKernelGGL(face_prep, dim3((NF + 255) / 256), dim3(256), 0, stream,
                       cam, verts, faces, fdat, cf, cbb, fcnt);
    hipLaunchKernelGGL(tex_sample, dim3((NF * 9 + 255) / 256), dim3(256), 0, stream,
                       cam, verts, faces, uv, out_tex);
    hipLaunchKernelGGL(bin_faces, dim3((NF * 32) / 256), dim3(256), 0, stream,
                       cf, cbb, fcnt, cnt, list, cap);
    hipLaunchKernelGGL(raster_score, dim3(4096), dim3(256), 0, stream,
                       cf, cnt, list, cap, keys);
    hipLaunchKernelGGL(epilogue, dim3(256), dim3(256), 0, stream,
                       keys, fdat, out_tex, out_img);
}

// Round 6
// 401.503 us; speedup vs baseline: 2.7224x; 2.7224x over previous
//
#include <hip/hip_runtime.h>
#include <hip/hip_bf16.h>

typedef unsigned long long u64;

static constexpr int NF = 27552;              // 2*13776 faces
static constexpr int IMGOFF = 3 * 256 * 256;  // image elements before textures
static constexpr int NSLICE = 16;             // list-slices per tile
static constexpr int CAPMAX = 6144;           // per-tile list capacity (max)

#define EYEZ 2.7320508075688772f   // -(EYE.z) = 1/tan(30deg)+1, fp64->fp32

// ws layout (bytes):
static constexpr size_t OFF_KEYS = 0;         // 65536 u64
static constexpr size_t OFF_FCNT = 524288;    // int (+pad)
static constexpr size_t OFF_CNT  = 524352;    // 1024 int per-tile counts
static constexpr size_t OFF_CF   = 528448;    // NF*16 f32 exact consts
static constexpr size_t OFF_CFS  = 2291776;   // NF*16 f32 scaled fast consts
static constexpr size_t OFF_CBB  = 4055104;   // NF float4 bboxes
static constexpr size_t OFF_LIST = 4495936;   // 1024*cap int  (same as r5)

static constexpr u64 FARKEY = ((u64)0x42C80000u << 32);  // depth=100.0f, id 0

// ---------------------------------------------------------------------------
// Kernel 0: init keys to FAR, zero per-tile counts and compaction counter.
// ---------------------------------------------------------------------------
__global__ __launch_bounds__(256) void init_ws(u64* __restrict__ keys,
                                               int* __restrict__ fcnt,
                                               int* __restrict__ cnt)
{
    int i = blockIdx.x * 256 + threadIdx.x;
    keys[i] = FARKEY;
    if (i < 1024) cnt[i] = 0;
    if (i == 0) *fcnt = 0;
}

// ---------------------------------------------------------------------------
// Kernel 1: per-face constants.  Exact block cf[p*16] (numpy op order, no FMA
// contraction -> bit-identical depth path):
//   a0,a1,a2,b0,b1,b2,c0,c1,c2,ds,iz0,iz1,iz2,idbits,0,0
// Fast block cfs[p*16] (ds-prescaled, approx-only, with error margin EM):
//   a0s,b0s,c0s,iz0, a1s,b1s,c1s,iz1, a2s,b2s,c2s,iz2, EM,idbits,0,0
// ---------------------------------------------------------------------------
__global__ __launch_bounds__(256) void face_prep(
    const float* __restrict__ cam,
    const float* __restrict__ verts,
    const int* __restrict__ faces,
    float* __restrict__ cf,
    float* __restrict__ cfs,
    float4* __restrict__ cbb,
    int* __restrict__ fcnt)
{
    int f = blockIdx.x * 256 + threadIdx.x;
    if (f >= NF) return;
    float c0 = cam[0], c1 = cam[1], c2 = cam[2];
    // replicate np look_at rounding exactly (these are 1.0 in binary FP, free)
    float z3 = __fdiv_rn(EYEZ, __fsqrt_rn(__fmul_rn(EYEZ, EYEZ)));
    float x0r = __fdiv_rn(z3, __fsqrt_rn(__fmul_rn(z3, z3)));
    float wyy = __fmul_rn(z3, x0r);
    float y1r = __fdiv_rn(wyy, __fsqrt_rn(__fmul_rn(wyy, wyy)));

    float xs[3], ys[3], zs[3];
#pragma unroll
    for (int i = 0; i < 3; i++) {
        int vi = faces[f * 3 + i];
        float vx = verts[vi * 3 + 0];
        float vy = verts[vi * 3 + 1];
        float vz = verts[vi * 3 + 2];
        float px = __fmul_rn(c0, __fadd_rn(vx, c1));
        float py = __fmul_rn(c0, __fadd_rn(vy, c2));
        xs[i] = __fmul_rn(px, x0r);
        ys[i] = __fmul_rn(-py, y1r);
        zs[i] = __fmul_rn(__fadd_rn(vz, EYEZ), z3);
    }
    float a0 = __fsub_rn(ys[1], ys[2]);
    float a1 = __fsub_rn(ys[2], ys[0]);
    float a2 = __fsub_rn(ys[0], ys[1]);
    float b0 = __fsub_rn(xs[2], xs[1]);
    float b1 = __fsub_rn(xs[0], xs[2]);
    float b2 = __fsub_rn(xs[1], xs[0]);
    float cc0 = __fsub_rn(__fmul_rn(xs[1], ys[2]), __fmul_rn(xs[2], ys[1]));
    float cc1 = __fsub_rn(__fmul_rn(xs[2], ys[0]), __fmul_rn(xs[0], ys[2]));
    float cc2 = __fsub_rn(__fmul_rn(xs[0], ys[1]), __fmul_rn(xs[1], ys[0]));
    float det = __fadd_rn(__fadd_rn(cc0, cc1), cc2);
    if (det <= 0.0f) return;   // back faces can never be `valid` -> exact cull
    float ds  = (fabsf(det) > 1e-10f) ? det : 1e-10f;
    float z0 = (fabsf(zs[0]) > 1e-6f) ? zs[0] : 1e-6f;
    float z1 = (fabsf(zs[1]) > 1e-6f) ? zs[1] : 1e-6f;
    float z2 = (fabsf(zs[2]) > 1e-6f) ? zs[2] : 1e-6f;
    float iz0 = __fdiv_rn(1.0f, z0);
    float iz1 = __fdiv_rn(1.0f, z1);
    float iz2 = __fdiv_rn(1.0f, z2);

    int pos = atomicAdd(fcnt, 1);
    float* q = cf + (size_t)pos * 16;
    q[0] = a0; q[1] = a1; q[2] = a2;
    q[3] = b0; q[4] = b1; q[5] = b2;
    q[6] = cc0; q[7] = cc1; q[8] = cc2;
    q[9] = ds;
    q[10] = iz0; q[11] = iz1; q[12] = iz2;
    q[13] = __int_as_float(f);
    q[14] = 0.0f; q[15] = 0.0f;

    // scaled fast block (approx-only; any rounding fine)
    float a0s = a0 / ds, a1s = a1 / ds, a2s = a2 / ds;
    float b0s = b0 / ds, b1s = b1 / ds, b2s = b2 / ds;
    float c0s = cc0 / ds, c1s = cc1 / ds, c2s = cc2 / ds;
    float S0 = fabsf(a0s) + fabsf(b0s) + fabsf(c0s);
    float S1 = fabsf(a1s) + fabsf(b1s) + fabsf(c1s);
    float S2 = fabsf(a2s) + fabsf(b2s) + fabsf(c2s);
    // EM bounds both |t'-w| and |dena-den| (conservative ~10x over true err)
    float EM = 4e-7f * (S0 * (iz0 + 1.0f) + S1 * (iz1 + 1.0f) + S2 * (iz2 + 1.0f))
             + 3e-5f;
    float* s = cfs + (size_t)pos * 16;
    s[0] = a0s; s[1] = b0s; s[2] = c0s; s[3] = iz0;
    s[4] = a1s; s[5] = b1s; s[6] = c1s; s[7] = iz1;
    s[8] = a2s; s[9] = b2s; s[10] = c2s; s[11] = iz2;
    s[12] = EM; s[13] = __int_as_float(f); s[14] = 0.0f; s[15] = 0.0f;

    float4 bb;
    bb.x = fminf(fminf(xs[0], xs[1]), xs[2]) - 1e-4f;
    bb.y = fmaxf(fmaxf(xs[0], xs[1]), xs[2]) + 1e-4f;
    bb.z = fminf(fminf(ys[0], ys[1]), ys[2]) - 1e-4f;
    bb.w = fmaxf(fmaxf(ys[0], ys[1]), ys[2]) + 1e-4f;
    cbb[pos] = bb;
}

// ---------------------------------------------------------------------------
// Kernel 2: 9 bilinear texture samples per face -> textures output (fp32).
// lighting() is the identity (DIR_INT=0, AMB=1).  3rd TS dim is broadcast.
// ---------------------------------------------------------------------------
__global__ __launch_bounds__(256) void tex_sample(
    const float* __restrict__ cam,
    const float* __restrict__ verts,
    const int* __restrict__ faces,
    const float* __restrict__ uv,
    float* __restrict__ out_tex)
{
    int id = blockIdx.x * 256 + threadIdx.x;
    if (id >= NF * 9) return;
    int f = id / 9, t = id - f * 9;
    float c0 = cam[0], c1 = cam[1], c2 = cam[2];
    float px[3], py[3];
#pragma unroll
    for (int i = 0; i < 3; i++) {
        int vi = faces[f * 3 + i];
        px[i] = __fmul_rn(c0, __fadd_rn(verts[vi * 3 + 0], c1));
        py[i] = __fmul_rn(c0, __fadd_rn(verts[vi * 3 + 1], c2));
    }
    const float abv[3] = {0.0f, 0.5f, 1.0f};
    int t1 = t / 3, t2 = t - t1 * 3;
    float uu = abv[t1], vv = abv[t2];
    float sx = __fadd_rn(__fadd_rn(__fmul_rn(__fsub_rn(px[0], px[2]), uu),
                                   __fmul_rn(__fsub_rn(px[1], px[2]), vv)), px[2]);
    float sy = __fadd_rn(__fadd_rn(__fmul_rn(__fsub_rn(py[0], py[2]), uu),
                                   __fmul_rn(__fsub_rn(py[1], py[2]), vv)), py[2]);
    sx = fminf(fmaxf(sx, -1.0f), 1.0f);
    sy = fminf(fmaxf(sy, -1.0f), 1.0f);
    float xg = __fmul_rn(__fmul_rn(__fadd_rn(sx, 1.0f), 0.5f), 255.0f);
    float yg = __fmul_rn(__fmul_rn(__fadd_rn(sy, 1.0f), 0.5f), 255.0f);
    float x0f = floorf(xg), y0f = floorf(yg);
    float wx = __fsub_rn(xg, x0f), wy = __fsub_rn(yg, y0f);
    int x0 = (int)x0f; x0 = x0 < 0 ? 0 : (x0 > 255 ? 255 : x0);
    int y0 = (int)y0f; y0 = y0 < 0 ? 0 : (y0 > 255 ? 255 : y0);
    int x1 = x0 + 1 > 255 ? 255 : x0 + 1;
    int y1 = y0 + 1 > 255 ? 255 : y0 + 1;
    float omwx = __fsub_rn(1.0f, wx), omwy = __fsub_rn(1.0f, wy);
    float w00 = __fmul_rn(omwx, omwy);
    float w10 = __fmul_rn(wx, omwy);
    float w01 = __fmul_rn(omwx, wy);
    float w11 = __fmul_rn(wx, wy);
    size_t tb = (size_t)f * 81 + (size_t)t1 * 27 + (size_t)t2 * 9;
#pragma unroll
    for (int c = 0; c < 3; c++) {
        const float* img = uv + c * 65536;
        float g00 = img[y0 * 256 + x0];
        float g10 = img[y0 * 256 + x1];
        float g01 = img[y1 * 256 + x0];
        float g11 = img[y1 * 256 + x1];
        float val = __fmul_rn(g00, w00);
        val = __fadd_rn(val, __fmul_rn(g10, w10));
        val = __fadd_rn(val, __fmul_rn(g01, w01));
        val = __fadd_rn(val, __fmul_rn(g11, w11));
        out_tex[tb + 0 + c] = val;
        out_tex[tb + 3 + c] = val;
        out_tex[tb + 6 + c] = val;
    }
}

// ---------------------------------------------------------------------------
// Kernel 3: binning, wave-aggregated. Wave = (tile-row jy, 64 consecutive
// faces). For each of the 32 columns (wave-uniform): per-lane SAT test,
// ballot, ONE atomicAdd per (wave,col), prefix-scatter (coalesced). SAT
// margin 1e-3 >> fp err -> list is a superset; extras scored exactly.
// ---------------------------------------------------------------------------
__global__ __launch_bounds__(256, 8) void bin_faces(
    const float* __restrict__ cf,
    const float4* __restrict__ cbb,
    const int* __restrict__ fcnt,
    int* __restrict__ cnt,
    int* __restrict__ list,
    int cap)
{
    const int lane = threadIdx.x & 63;
    const int w = blockIdx.x * 4 + (threadIdx.x >> 6);   // 0..6911
    const int jy = w / 216;                              // tile row 0..31
    const int p  = (w - jy * 216) * 64 + lane;           // face index
    const int n = *fcnt;
    const float ylo = (float)(16 * jy + 1 - 256) * (1.0f / 256.0f);
    const float yhi = (float)(16 * jy + 15 - 256) * (1.0f / 256.0f);

    bool rv = (p < n);
    float A0 = 0, A1 = 0, A2 = 0, B0 = 0, B1 = 0, B2 = 0;
    int jx0 = 32, jx1 = -1;
    if (rv) {
        float4 bb = cbb[p];
        rv = (yhi >= bb.z) && (ylo <= bb.w);
        if (rv) {
            const float4* q = (const float4*)(cf + (size_t)p * 16);
            float4 q0 = q[0], q1 = q[1], q2 = q[2];
            float a0 = q0.x, a1 = q0.y, a2 = q0.z;
            float b0 = q0.w, b1 = q1.x, b2 = q1.y;
            float c0 = q1.z, c1 = q1.w, c2 = q2.x;
            float K0 = fmaxf(b0 * ylo, b0 * yhi) + c0;
            float K1 = fmaxf(b1 * ylo, b1 * yhi) + c1;
            float K2 = fmaxf(b2 * ylo, b2 * yhi) + c2;
            A0 = a0 * (1.0f / 16.0f);
            A1 = a1 * (1.0f / 16.0f);
            A2 = a2 * (1.0f / 16.0f);
            B0 = a0 * (((a0 > 0.f ? 15.f : 1.f) - 256.f) * (1.0f / 256.0f)) + K0;
            B1 = a1 * (((a1 > 0.f ? 15.f : 1.f) - 256.f) * (1.0f / 256.0f)) + K1;
            B2 = a2 * (((a2 > 0.f ? 15.f : 1.f) - 256.f) * (1.0f / 256.0f)) + K2;
            jx0 = (int)floorf(16.0f * bb.x + 15.0625f);
            jx1 = (int)floorf(16.0f * bb.y + 15.9375f) + 1;
            jx0 = jx0 < 0 ? 0 : jx0;
            jx1 = jx1 > 31 ? 31 : jx1;
        }
    }
    if (__ballot(rv) == 0ull) return;

    for (int jx = 0; jx < 32; jx++) {
        float jf = (float)jx;
        bool pass = rv && (jx >= jx0) && (jx <= jx1) &&
                    (fmaf(jf, A0, B0) >= -1e-3f) &&
                    (fmaf(jf, A1, B1) >= -1e-3f) &&
                    (fmaf(jf, A2, B2) >= -1e-3f);
        u64 mk = __ballot(pass);
        if (mk) {
            int leader = __ffsll((long long)mk) - 1;
            int nadd = __popcll(mk);
            int pref = __popcll(mk & ((1ull << lane) - 1ull));
            int base = 0;
            if (lane == leader) base = atomicAdd(&cnt[jy * 32 + jx], nadd);
            base = __shfl(base, leader);
            int pos = base + pref;
            if (pass && pos < cap)
                list[(size_t)(jy * 32 + jx) * cap + pos] = p;
        }
    }
}

// ---------------------------------------------------------------------------
// Kernel 4: depth argmin over binned lists with a divide-free fast filter.
// Wave = (8x8 tile, slice). Per 64-entry chunk: gather fast+exact blocks to
// LDS (transposed), then per candidate: approx barycentric/den tests + a
// running approx max-den gate. Only potential winners run the bit-exact
// numpy path (4 IEEE divides). Filter-reject => exact-reject (margins EM).
// Winner key = (zp_bits<<32)|orig_id via global atomicMin.
// ---------------------------------------------------------------------------
__global__ __launch_bounds__(256, 4) void raster_score(
    const float* __restrict__ cf,
    const float* __restrict__ cfs,
    const int* __restrict__ cnt,
    const int* __restrict__ list,
    int cap,
    u64* __restrict__ keys)
{
    __shared__ __align__(16) float sfast[4][1024];
    __shared__ __align__(16) float sexact[4][1024];
    const int lane = threadIdx.x & 63;
    const int wid  = threadIdx.x >> 6;
    const int gw = blockIdx.x * 4 + wid;             // 0..16383
    const int tile = gw & 1023;
    const int slice = gw >> 10;                      // 16 slices
    const int tx = tile & 31, ty = tile >> 5;
    const int pxi = tx * 8 + (lane & 7), pyi = ty * 8 + (lane >> 3);
    const float xp = (float)(2 * pxi + 1 - 256) * (1.0f / 256.0f);  // exact
    const float yp = (float)(2 * pyi + 1 - 256) * (1.0f / 256.0f);
    float* sf = sfast[wid];
    float* se = sexact[wid];

    int len = cnt[tile];
    if (len > cap) len = cap;
    const int per = (len + NSLICE - 1) / NSLICE;
    const int s0 = slice * per;
    const int s1 = (s0 + per < len) ? s0 + per : len;
    if (s0 >= s1) return;
    const int* tl = list + (size_t)tile * cap;

    u64 best = FARKEY;
    float dmax = 0.0f;                 // running approx max den (valid only)
    float ibf  = 0.00984f;             // (1/100)*0.994 - 1e-4
    float thr  = ibf;

    // preload chunk 0
    bool cv = (s0 + lane) < s1;
    float4 f0, f1, f2, f3, e0, e1, e2, e3;
    if (cv) {
        int cid = tl[s0 + lane];
        const float4* fp4 = (const float4*)(cfs + (size_t)cid * 16);
        f0 = fp4[0]; f1 = fp4[1]; f2 = fp4[2]; f3 = fp4[3];
        const float4* ep4 = (const float4*)(cf + (size_t)cid * 16);
        e0 = ep4[0]; e1 = ep4[1]; e2 = ep4[2]; e3 = ep4[3];
    }

    for (int cb = s0; cb < s1; cb += 64) {
        int m = s1 - cb; if (m > 64) m = 64;
        if (cv) {
            *(float4*)(sf +   0 + lane * 4) = f0;
            *(float4*)(sf + 256 + lane * 4) = f1;
            *(float4*)(sf + 512 + lane * 4) = f2;
            *(float4*)(sf + 768 + lane * 4) = f3;
            *(float4*)(se +   0 + lane * 4) = e0;
            *(float4*)(se + 256 + lane * 4) = e1;
            *(float4*)(se + 512 + lane * 4) = e2;
            *(float4*)(se + 768 + lane * 4) = e3;
        }
        int nb = cb + 64;
        cv = false;
        if (nb < s1) {
            cv = (nb + lane) < s1;
            if (cv) {
                int nid = tl[nb + lane];
                const float4* fp4 = (const float4*)(cfs + (size_t)nid * 16);
                f0 = fp4[0]; f1 = fp4[1]; f2 = fp4[2]; f3 = fp4[3];
                const float4* ep4 = (const float4*)(cf + (size_t)nid * 16);
                e0 = ep4[0]; e1 = ep4[1]; e2 = ep4[2]; e3 = ep4[3];
            }
        }
        asm volatile("s_waitcnt lgkmcnt(0)" ::: "memory");

        for (int j = 0; j < m; j++) {
            const float* fb = sf + 4 * j;
            float4 v0 = *(const float4*)(fb);         // a0s,b0s,c0s,iz0
            float4 v1 = *(const float4*)(fb + 256);   // a1s,b1s,c1s,iz1
            float4 v2 = *(const float4*)(fb + 512);   // a2s,b2s,c2s,iz2
            float  EM = fb[768];
            float t0 = fmaf(xp, v0.x, fmaf(yp, v0.y, v0.z));  // ~ w0
            float t1 = fmaf(xp, v1.x, fmaf(yp, v1.y, v1.z));
            float t2 = fmaf(xp, v2.x, fmaf(yp, v2.y, v2.z));
            float dena = fmaf(t2, v2.w, fmaf(t1, v1.w, t0 * v0.w));
            float nEM = -EM, opEM = 1.0f + EM;
            bool pass = (t0 >= nEM) && (t1 >= nEM) && (t2 >= nEM) &&
                        (t0 <= opEM) && (t1 <= opEM) && (t2 <= opEM) &&
                        (dena >= 0.0099f - EM) && (dena <= 10.001f + EM) &&
                        (dena + EM >= thr);
            // strict validity for the running max (certainly-valid only)
            float es = EM + 1e-6f, oms = 1.0f - EM - 1e-6f;
            bool sok = (t0 >= es) && (t1 >= es) && (t2 >= es) &&
                       (t0 <= oms) && (t1 <= oms) && (t2 <= oms) &&
                       (dena >= 0.0101f + EM) && (dena <= 9.99f - EM) &&
                       (EM <= 1e-3f);
            if (sok) dmax = fmaxf(dmax, dena);
            thr = fmaxf(fmaf(dmax, 0.996f, -2e-3f), ibf);
            if (__any(pass)) {
                const float* eb = se + 4 * j;
                float4 q0 = *(const float4*)(eb);        // a0,a1,a2,b0
                float4 q1 = *(const float4*)(eb + 256);  // b1,b2,c0,c1
                float4 q2 = *(const float4*)(eb + 512);  // c2,ds,iz0,iz1
                float2 q3 = *(const float2*)(eb + 768);  // iz2,idbits
                // bit-exact numpy path
                float x0 = __fadd_rn(__fadd_rn(__fmul_rn(xp, q0.x), __fmul_rn(yp, q0.w)), q1.z);
                float x1 = __fadd_rn(__fadd_rn(__fmul_rn(xp, q0.y), __fmul_rn(yp, q1.x)), q1.w);
                float x2 = __fadd_rn(__fadd_rn(__fmul_rn(xp, q0.z), __fmul_rn(yp, q1.y)), q2.x);
                bool in = !(x0 < 0.0f) && !(x1 < 0.0f) && !(x2 < 0.0f);
                if (__any(in)) {
                    float dsf = q2.y;
                    float w0 = __fdiv_rn(x0, dsf);
                    float w1 = __fdiv_rn(x1, dsf);
                    float w2 = __fdiv_rn(x2, dsf);
                    in = in && !(w0 > 1.0f) && !(w1 > 1.0f) && !(w2 > 1.0f);
                    float den = __fmul_rn(w0, q2.z);
                    den = __fadd_rn(den, __fmul_rn(w1, q2.w));
                    den = __fadd_rn(den, __fmul_rn(w2, q3.x));
                    if (in && den > 1e-8f) {
                        float zp = __fdiv_rn(1.0f, den);
                        if (zp > 0.1f && zp < 100.0f) {
                            u64 key = ((u64)__float_as_uint(zp) << 32)
                                    | (u64)(unsigned)__float_as_int(q3.y);
                            if (key < best) {
                                best = key;
                                float bfv = __uint_as_float((unsigned)(best >> 32));
                                ibf = (1.0f / bfv) * 0.994f - 1e-4f;
                                thr = fmaxf(thr, ibf);
                            }
                        }
                    }
                }
            }
        }
    }
    if (best != FARKEY)
        atomicMin(&keys[(size_t)pyi * 256 + pxi], best);
}

// ---------------------------------------------------------------------------
// Kernel 5: per-pixel epilogue — recompute the winner face's constants from
// the raw inputs (bit-exact face_prep replica), exact barycentrics, then
// trilinear-sample the face texture (numpy op order).
// ---------------------------------------------------------------------------
__global__ __launch_bounds__(256) void epilogue(
    const u64* __restrict__ keys,
    const float* __restrict__ cam,
    const float* __restrict__ verts,
    const int* __restrict__ faces,
    const float* __restrict__ tex,   // d_out + IMGOFF, from tex_sample
    float* __restrict__ out_img)
{
    int pix = blockIdx.x * 256 + threadIdx.x;   // 65536
    int xo = pix & 255, yo = pix >> 8;
    const float xp = (float)(2 * xo + 1 - 256) * (1.0f / 256.0f);
    const float yp = (float)(2 * yo + 1 - 256) * (1.0f / 256.0f);
    u64 m = keys[pix];
    float depth = __uint_as_float((unsigned)(m >> 32));
    float col0 = 0.f, col1 = 0.f, col2 = 0.f;
    if (depth < 100.0f) {
        int fidx = (int)(unsigned)(m & 0xFFFFFFFFu);
        float c0 = cam[0], c1 = cam[1], c2 = cam[2];
        float z3 = __fdiv_rn(EYEZ, __fsqrt_rn(__fmul_rn(EYEZ, EYEZ)));
        float x0r = __fdiv_rn(z3, __fsqrt_rn(__fmul_rn(z3, z3)));
        float wyy = __fmul_rn(z3, x0r);
        float y1r = __fdiv_rn(wyy, __fsqrt_rn(__fmul_rn(wyy, wyy)));
        float xs[3], ys[3], zs[3];
#pragma unroll
        for (int i = 0; i < 3; i++) {
            int vi = faces[fidx * 3 + i];
            float vx = verts[vi * 3 + 0];
            float vy = verts[vi * 3 + 1];
            float vz = verts[vi * 3 + 2];
            float px = __fmul_rn(c0, __fadd_rn(vx, c1));
            float py = __fmul_rn(c0, __fadd_rn(vy, c2));
            xs[i] = __fmul_rn(px, x0r);
            ys[i] = __fmul_rn(-py, y1r);
            zs[i] = __fmul_rn(__fadd_rn(vz, EYEZ), z3);
        }
        float a0 = __fsub_rn(ys[1], ys[2]);
        float a1 = __fsub_rn(ys[2], ys[0]);
        float a2 = __fsub_rn(ys[0], ys[1]);
        float b0 = __fsub_rn(xs[2], xs[1]);
        float b1 = __fsub_rn(xs[0], xs[2]);
        float b2 = __fsub_rn(xs[1], xs[0]);
        float cc0 = __fsub_rn(__fmul_rn(xs[1], ys[2]), __fmul_rn(xs[2], ys[1]));
        float cc1 = __fsub_rn(__fmul_rn(xs[2], ys[0]), __fmul_rn(xs[0], ys[2]));
        float cc2 = __fsub_rn(__fmul_rn(xs[0], ys[1]), __fmul_rn(xs[1], ys[0]));
        float det = __fadd_rn(__fadd_rn(cc0, cc1), cc2);
        float dsf = (fabsf(det) > 1e-10f) ? det : 1e-10f;
        float z0 = (fabsf(zs[0]) > 1e-6f) ? zs[0] : 1e-6f;
        float z1 = (fabsf(zs[1]) > 1e-6f) ? zs[1] : 1e-6f;
        float z2 = (fabsf(zs[2]) > 1e-6f) ? zs[2] : 1e-6f;

        float t0 = __fadd_rn(__fadd_rn(__fmul_rn(xp, a0), __fmul_rn(yp, b0)), cc0);
        float t1 = __fadd_rn(__fadd_rn(__fmul_rn(xp, a1), __fmul_rn(yp, b1)), cc1);
        float t2 = __fadd_rn(__fadd_rn(__fmul_rn(xp, a2), __fmul_rn(yp, b2)), cc2);
        float w0 = __fdiv_rn(t0, dsf), w1 = __fdiv_rn(t1, dsf), w2 = __fdiv_rn(t2, dsf);
        float wc0 = __fdiv_rn(w0, z0);
        float wc1 = __fdiv_rn(w1, z1);
        float wc2 = __fdiv_rn(w2, z2);
        float ssum = __fadd_rn(__fadd_rn(wc0, wc1), wc2);
        float dnm = fmaxf(ssum, 1e-8f);
        wc0 = __fdiv_rn(wc0, dnm); wc1 = __fdiv_rn(wc1, dnm); wc2 = __fdiv_rn(wc2, dnm);
        float pos0 = __fmul_rn(fminf(fmaxf(wc0, 0.f), 1.f), 2.0f);
        float pos1 = __fmul_rn(fminf(fmaxf(wc1, 0.f), 1.f), 2.0f);
        float pos2 = __fmul_rn(fminf(fmaxf(wc2, 0.f), 1.f), 2.0f);
        float lf0 = fminf(fmaxf(floorf(pos0), 0.f), 2.f);
        float lf1 = fminf(fmaxf(floorf(pos1), 0.f), 2.f);
        float lf2 = fminf(fmaxf(floorf(pos2), 0.f), 2.f);
        float fr0 = __fsub_rn(pos0, lf0), fr1 = __fsub_rn(pos1, lf1), fr2 = __fsub_rn(pos2, lf2);
        int lo0 = (int)lf0, lo1 = (int)lf1;
        int hi0 = lo0 + 1 > 2 ? 2 : lo0 + 1;
        int hi1 = lo1 + 1 > 2 ? 2 : lo1 + 1;
        const float* tbase = tex + (size_t)fidx * 81;
#pragma unroll
        for (int bits = 0; bits < 8; bits++) {
            int u0 = bits & 1, u1 = (bits >> 1) & 1, u2 = (bits >> 2) & 1;
            int i0 = u0 ? hi0 : lo0;
            int i1 = u1 ? hi1 : lo1;
            float e0 = u0 ? fr0 : __fsub_rn(1.0f, fr0);
            float e1 = u1 ? fr1 : __fsub_rn(1.0f, fr1);
            float e2 = u2 ? fr2 : __fsub_rn(1.0f, fr2);
            float wgt = __fmul_rn(__fmul_rn(e0, e1), e2);
            const float* tp = tbase + (size_t)i0 * 27 + (size_t)i1 * 9;  // k broadcast
            col0 = __fadd_rn(col0, __fmul_rn(wgt, tp[0]));
            col1 = __fadd_rn(col1, __fmul_rn(wgt, tp[1]));
            col2 = __fadd_rn(col2, __fmul_rn(wgt, tp[2]));
        }
    }
    out_img[pix]          = col0;
    out_img[65536 + pix]  = col1;
    out_img[131072 + pix] = col2;
}

extern "C" void kernel_launch(void* const* d_in, const int* in_sizes, int n_in,
                              void* d_out, int out_size, void* d_ws, size_t ws_size,
                              hipStream_t stream) {
    const float* cam   = (const float*)d_in[0];
    const float* verts = (const float*)d_in[1];
    const float* uv    = (const float*)d_in[2];
    const int*   faces = (const int*)d_in[3];
    float* out = (float*)d_out;

    char* ws = (char*)d_ws;
    u64*    keys = (u64*)(ws + OFF_KEYS);
    int*    fcnt = (int*)(ws + OFF_FCNT);
    int*    cntp = (int*)(ws + OFF_CNT);
    float*  cf   = (float*)(ws + OFF_CF);
    float*  cfs  = (float*)(ws + OFF_CFS);
    float4* cbb  = (float4*)(ws + OFF_CBB);
    int*    list = (int*)(ws + OFF_LIST);

    int cap = CAPMAX;
    if (ws_size > OFF_LIST) {
        size_t avail = (ws_size - OFF_LIST) / (1024 * sizeof(int));
        if ((size_t)cap > avail) cap = (int)avail;
    } else {
        cap = 0;
    }

    float* out_img = out;            // 3*256*256
    float* out_tex = out + IMGOFF;   // NF*81

    hipLaunchKernelGGL(init_ws, dim3(256), dim3(256), 0, stream, keys, fcnt, cntp);
    hipLaunchKernelGGL(face_prep, dim3((NF + 255) / 256), dim3(256), 0, stream,
                       cam, verts, faces, cf, cfs, cbb, fcnt);
    hipLaunchKernelGGL(tex_sample, dim3((NF * 9 + 255) / 256), dim3(256), 0, stream,
                       cam, verts, faces, uv, out_tex);
    hipLaunchKernelGGL(bin_faces, dim3(1728), dim3(256), 0, stream,
                       cf, cbb, fcnt, cntp, list, cap);
    hipLaunchKernelGGL(raster_score, dim3(4096), dim3(256), 0, stream,
                       cf, cfs, cntp, list, cap, keys);
    hipLaunchKernelGGL(epilogue, dim3(256), dim3(256), 0, stream,
                       keys, cam, verts, faces, out_tex, out_img);
}